// Round 14
// baseline (175.198 us; speedup 1.0000x reference)
//
#include <hip/hip_runtime.h>
#include <hip/hip_bf16.h>

typedef __hip_bfloat16 bf16;
typedef __hip_bfloat162 bf162;
typedef _Float16 f16;
typedef __attribute__((ext_vector_type(2))) _Float16 h2;
typedef __attribute__((ext_vector_type(8))) short short8;
typedef __attribute__((ext_vector_type(4))) float f32x4;

#define B_ 4
#define R_ 512
#define C_ 512
#define E_ 256
#define H_ 16
#define D_ 16

__device__ __forceinline__ float b2f(bf16 x) { return __bfloat162float(x); }
__device__ __forceinline__ void stout(bf16* p, float v) { *p = __float2bfloat16(v); }
__device__ __forceinline__ void stout(f16* p, float v) { *p = (f16)v; }

// ================= MFMA GEMM body =================
// A: AMODE 0 = bf16, 1 = fp32 (cvt on stage), 2 = instance-norm bf16 (normS,g,b)
// B: always fp32 W[K][N], transpose+cvt(+bscl) during staging (no pre-transpose pass)
// RES: 0 none, 1 fp32 ptr, 3 instance-norm(bf16 Res); STATS: sum/sumsq atomics
template <int AMODE, typename OT, int BM, int BN, bool BIAS, int RES, bool RELU, bool STATS>
__device__ __forceinline__ void mfma_gemm_body(
    const void* __restrict__ Ap, const float* __restrict__ W, float bscl,
    const float* __restrict__ bias, const void* __restrict__ Res,
    const float* __restrict__ normS, const float* __restrict__ normG, const float* __restrict__ normB,
    float* __restrict__ statsOut, OT* __restrict__ Cout,
    int M, int N, int K, int bx, int by)
{
    constexpr int MT = BM / 32, NT = BN / 32;
    constexpr int AEL = BM * 64 / 256, BEL = BN * 64 / 256;
    __shared__ __align__(16) bf16 As[BM * 80];
    __shared__ __align__(16) bf16 Bs[BN * 80];
    const int tid = threadIdx.x;
    const int wid = tid >> 6, lane = tid & 63;
    const int wm = wid >> 1, wn = wid & 1;
    const int fr = lane & 15, quad = lane >> 4;
    const int m0 = by * BM, n0 = bx * BN;
    const int arow = (AEL == 16) ? (tid >> 2) : (tid >> 3);
    const int akg  = (AEL == 16) ? ((tid & 3) << 4) : ((tid & 7) << 3);
    const int brow = (BEL == 16) ? (tid >> 2) : (tid >> 3);
    const int bkg  = (BEL == 16) ? ((tid & 3) << 4) : ((tid & 7) << 3);

    f32x4 acc[MT][NT];
#pragma unroll
    for (int mt = 0; mt < MT; mt++)
#pragma unroll
        for (int nt = 0; nt < NT; nt++) acc[mt][nt] = (f32x4){0.f, 0.f, 0.f, 0.f};

    for (int k0 = 0; k0 < K; k0 += 64) {
        // ---- stage A ----
        if constexpr (AMODE == 0) {
            const short8* gp = (const short8*)((const bf16*)Ap + (size_t)(m0 + arow) * K + k0 + akg);
#pragma unroll
            for (int t8 = 0; t8 < AEL / 8; t8++) *(short8*)(&As[arow * 80 + akg + 8 * t8]) = gp[t8];
        } else if constexpr (AMODE == 1) {
            const float4* gp = (const float4*)((const float*)Ap + (size_t)(m0 + arow) * K + k0 + akg);
#pragma unroll
            for (int j = 0; j < AEL / 4; j++) {
                const float4 f = gp[j];
                *(bf162*)(&As[arow * 80 + akg + j * 4])     = __float22bfloat162_rn(make_float2(f.x, f.y));
                *(bf162*)(&As[arow * 80 + akg + j * 4 + 2]) = __float22bfloat162_rn(make_float2(f.z, f.w));
            }
        } else {  // AMODE == 2: instance-norm A
            const int bb = (m0 + arow) >> 9;
            const bf16* ap = (const bf16*)Ap + (size_t)(m0 + arow) * K + k0 + akg;
            bf16 tmp[AEL];
#pragma unroll
            for (int t8 = 0; t8 < AEL / 8; t8++) *(short8*)(tmp + 8 * t8) = ((const short8*)ap)[t8];
#pragma unroll
            for (int j = 0; j < AEL; j++) {
                const int e = k0 + akg + j;
                const float s = normS[bb * 256 + e], sq = normS[1024 + bb * 256 + e];
                const float mn = s * (1.f / 512.f);
                float var = sq * (1.f / 512.f) - mn * mn; var = fmaxf(var, 0.f);
                As[arow * 80 + akg + j] = __float2bfloat16(
                    (b2f(tmp[j]) - mn) * rsqrtf(var + 1e-5f) * normG[e] + normB[e]);
            }
        }
        // ---- stage B: transpose+cvt from fp32 W[K][N] ----
        {
#pragma unroll
            for (int j = 0; j < BEL; j++)
                Bs[brow * 80 + bkg + j] = __float2bfloat16(
                    bscl * W[(size_t)(k0 + bkg + j) * N + (n0 + brow)]);
        }
        __syncthreads();

        short8 af[MT][2], bfr[NT][2];
#pragma unroll
        for (int mt = 0; mt < MT; mt++) {
            const int ar = wm * (BM / 2) + mt * 16 + fr;
#pragma unroll
            for (int kh = 0; kh < 2; kh++)
                af[mt][kh] = *(const short8*)(&As[ar * 80 + quad * 8 + kh * 32]);
        }
#pragma unroll
        for (int nt = 0; nt < NT; nt++) {
            const int br = wn * (BN / 2) + nt * 16 + fr;
#pragma unroll
            for (int kh = 0; kh < 2; kh++)
                bfr[nt][kh] = *(const short8*)(&Bs[br * 80 + quad * 8 + kh * 32]);
        }
#pragma unroll
        for (int kh = 0; kh < 2; kh++)
#pragma unroll
            for (int mt = 0; mt < MT; mt++)
#pragma unroll
                for (int nt = 0; nt < NT; nt++)
                    acc[mt][nt] = __builtin_amdgcn_mfma_f32_16x16x32_bf16(
                        af[mt][kh], bfr[nt][kh], acc[mt][nt], 0, 0, 0);
        __syncthreads();
    }

    // ---- epilogue (C/D: col=lane&15, row=quad*4+reg) ----
    float vsum[NT], vss[NT];
#pragma unroll
    for (int nt = 0; nt < NT; nt++) { vsum[nt] = 0.f; vss[nt] = 0.f; }
#pragma unroll
    for (int mt = 0; mt < MT; mt++) {
#pragma unroll
        for (int nt = 0; nt < NT; nt++) {
#pragma unroll
            for (int i = 0; i < 4; i++) {
                const int row = m0 + wm * (BM / 2) + mt * 16 + quad * 4 + i;
                const int col = n0 + wn * (BN / 2) + nt * 16 + fr;
                float v = acc[mt][nt][i];
                if (BIAS) v += bias[col];
                if constexpr (RES == 1) v += ((const float*)Res)[(size_t)row * N + col];
                if constexpr (RES == 3) {
                    const int bb = row >> 9;
                    const float yv = b2f(((const bf16*)Res)[(size_t)row * N + col]);
                    const float s = normS[bb * 256 + col], sq = normS[1024 + bb * 256 + col];
                    const float mn = s * (1.f / 512.f);
                    float var = sq * (1.f / 512.f) - mn * mn; var = fmaxf(var, 0.f);
                    v += (yv - mn) * rsqrtf(var + 1e-5f) * normG[col] + normB[col];
                }
                if (RELU) v = fmaxf(v, 0.f);
                stout(&Cout[(size_t)row * N + col], v);
                if (STATS) { vsum[nt] += v; vss[nt] += v * v; }
            }
        }
    }
    if constexpr (STATS) {
        float* sred = (float*)As;  // alias dead A-tile
#pragma unroll
        for (int nt = 0; nt < NT; nt++) {
            float a = vsum[nt]; a += __shfl_xor(a, 16, 64); a += __shfl_xor(a, 32, 64);
            float c = vss[nt];  c += __shfl_xor(c, 16, 64); c += __shfl_xor(c, 32, 64);
            if (quad == 0) {
                const int cl = wn * (BN / 2) + nt * 16 + fr;
                sred[wm * (2 * BN) + cl * 2 + 0] = a;
                sred[wm * (2 * BN) + cl * 2 + 1] = c;
            }
        }
        __syncthreads();
        if (tid < 2 * BN) {
            const int cl = tid >> 1, w = tid & 1;
            const float tot = sred[cl * 2 + w] + sred[2 * BN + cl * 2 + w];
            atomicAdd(&statsOut[w * 1024 + (m0 >> 9) * 256 + n0 + cl], tot);
        }
    }
}

template <int AMODE, typename OT, int BM, int BN, bool BIAS, int RES, bool RELU, bool STATS>
__global__ __launch_bounds__(256) void mfma_gemm_kernel(
    const void* __restrict__ Ap, const float* __restrict__ W, float bscl,
    const float* __restrict__ bias, const void* __restrict__ Res,
    const float* __restrict__ normS, const float* __restrict__ normG, const float* __restrict__ normB,
    float* __restrict__ statsOut, OT* __restrict__ Cout, int M, int N, int K)
{
    mfma_gemm_body<AMODE, OT, BM, BN, BIAS, RES, RELU, STATS>(
        Ap, W, bscl, bias, Res, normS, normG, normB, statsOut, Cout,
        M, N, K, blockIdx.x, blockIdx.y);
}

// ================= K1: fused QKV (direct fp32 W, transpose-on-stage) =================
// q,k -> f16 (for pk-f16 dot); v -> bf16 (for PV MFMA). Wq pre-scaled 0.25 via bscl.
__global__ __launch_bounds__(256) void qkv_kernel(
    const float* __restrict__ rowE, const float* __restrict__ colE,
    const float* __restrict__ Wq, const float* __restrict__ Wk, const float* __restrict__ Wv,
    f16* __restrict__ qo, f16* __restrict__ ko, bf16* __restrict__ vo)
{
    const int z = blockIdx.z;
    if (z == 2) {
        mfma_gemm_body<1, bf16, 32, 64, false, 0, false, false>(
            colE, Wv, 1.f, nullptr, nullptr, nullptr, nullptr, nullptr, nullptr, vo,
            2048, 256, 256, blockIdx.x, blockIdx.y);
    } else {
        mfma_gemm_body<1, f16, 32, 64, false, 0, false, false>(
            (z == 0) ? rowE : colE, (z == 0) ? Wq : Wk, (z == 0) ? 0.25f : 1.f,
            nullptr, nullptr, nullptr, nullptr, nullptr, nullptr, (z == 0) ? qo : ko,
            2048, 256, 256, blockIdx.x, blockIdx.y);
    }
}

// ================= K2: attention with MFMA PV; grid (rt8 x cs4, h16, b4) = 2048 WGs =================
// Wave w owns rows [rt*64+w*16, +16) x 128 cols. Lane computes scores at A-frag
// positions (m=lane&15, k=quad*8+j): its 8 softmax weights ARE the MFMA A-fragment.
// V is the B-fragment (k=quad*8+j, n=lane&15); O accumulates in C-regs
// (row=quad*4+i, col=lane&15). Two-pass per-row max -> p in (0,1] fits bf16.
// No intra-WG merge needed (waves own disjoint rows). 8.2 KB LDS.
__global__ __launch_bounds__(256) void attn_kernel(
    const f16* __restrict__ q, const f16* __restrict__ k, const bf16* __restrict__ v,
    const float* __restrict__ cost, const float* __restrict__ m1w, const float* __restrict__ m1b,
    const float* __restrict__ m2w, const float* __restrict__ m2b,
    bf16* __restrict__ po, float* __restrict__ plf)
{
    __shared__ __align__(16) f16 kbuf[128 * 16];    // 4 KB
    __shared__ __align__(16) short vbuf[128 * 16];  // 4 KB (bf16 bits)

    const int rt = blockIdx.x >> 2, cs = blockIdx.x & 3;
    const int h = blockIdx.y, b = blockIdx.z;
    const int tid = threadIdx.x, wid = tid >> 6, lane = tid & 63;
    const int quad = lane >> 4, fr = lane & 15;

    // ---- stage k (f16) and v (bf16) for 128 columns: straight copies ----
    {
        const size_t base = ((size_t)b * C_) * 256 + h * 16 + (size_t)cs * 128 * 256;
        const int lc = tid >> 1, dp = (tid & 1) * 8;
        const size_t g = base + (size_t)lc * 256 + dp;
        *(short8*)(&kbuf[lc * 16 + dp]) = *(const short8*)(k + g);
        *(short8*)(&vbuf[lc * 16 + dp]) = *(const short8*)(v + g);
    }

    // per-head MLP weights (packed f16 pairs over m)
    h2 w1a2[8], w1b2[8], b1h[8], w2p[8];
#pragma unroll
    for (int i = 0; i < 8; i++) {
        h2 t;
        t.x = (f16)m1w[h * 32 + 2 * i];      t.y = (f16)m1w[h * 32 + 2 * i + 1];      w1a2[i] = t;
        t.x = (f16)m1w[h * 32 + 16 + 2 * i]; t.y = (f16)m1w[h * 32 + 17 + 2 * i];     w1b2[i] = t;
        t.x = (f16)m1b[h * 16 + 2 * i];      t.y = (f16)m1b[h * 16 + 2 * i + 1];      b1h[i] = t;
        t.x = (f16)m2w[h * 16 + 2 * i];      t.y = (f16)m2w[h * 16 + 2 * i + 1];      w2p[i] = t;
    }
    const float b2v = m2b[h];
    const h2 zero2 = (h2)(f16)0;

    // this lane's q row (Wq carries the 0.25 scale)
    const int row_m = rt * 64 + wid * 16 + fr;
    short8 qraw[2];
    {
        const short8* qp = (const short8*)(q + (size_t)(b * R_ + row_m) * 256 + h * 16);
        qraw[0] = qp[0]; qraw[1] = qp[1];
    }
    const h2* qh = (const h2*)qraw;

    __syncthreads();

    // ---- pass 1: 32 scores at A-frag positions, buffered f16 ----
    const float* crow = cost + (size_t)(b * R_ + row_m) * C_ + cs * 128;
    h2 sh[16];
#pragma unroll
    for (int blk = 0; blk < 4; blk++) {
        const float4 c0 = *(const float4*)(crow + blk * 32 + quad * 8);
        const float4 c1 = *(const float4*)(crow + blk * 32 + quad * 8 + 4);
        const float carr[8] = {c0.x, c0.y, c0.z, c0.w, c1.x, c1.y, c1.z, c1.w};
#pragma unroll
        for (int j = 0; j < 8; j++) {
            const int col = blk * 32 + quad * 8 + j;
            const h2* kr = (const h2*)(&kbuf[col * 16]);
            h2 dacc = qh[0] * kr[0];
#pragma unroll
            for (int i = 1; i < 8; i++) dacc = qh[i] * kr[i] + dacc;
            const float dot = (float)dacc.x + (float)dacc.y;
            const float cst = carr[j];
            const f16 doth = (f16)dot, csth = (f16)cst;
            h2 dot2; dot2.x = doth; dot2.y = doth;
            h2 cst2; cst2.x = csth; cst2.y = csth;
            h2 acc2 = (h2)(f16)0;
#pragma unroll
            for (int i = 0; i < 8; i++) {
                h2 t = dot2 * w1a2[i] + b1h[i];
                t = cst2 * w1b2[i] + t;
                t = __builtin_elementwise_max(t, zero2);
                acc2 = t * w2p[i] + acc2;
            }
            const float s = b2v + (float)acc2.x + (float)acc2.y;
            const f16 sf = (f16)s;
            if (j & 1) sh[blk * 4 + (j >> 1)].y = sf;
            else       sh[blk * 4 + (j >> 1)].x = sf;
        }
    }

    // ---- row max (row = fr, shared across quads) ----
    h2 mx2 = sh[0];
#pragma unroll
    for (int i = 1; i < 16; i++) mx2 = __builtin_elementwise_max(mx2, sh[i]);
    float m_l = fmaxf((float)mx2.x, (float)mx2.y);
    m_l = fmaxf(m_l, __shfl_xor(m_l, 16, 64));
    m_l = fmaxf(m_l, __shfl_xor(m_l, 32, 64));

    // ---- pass 2: exp -> bf16 A-frag, V B-frag, MFMA PV ----
    f32x4 oacc = (f32x4){0.f, 0.f, 0.f, 0.f};
    float lsum = 0.f;
#pragma unroll
    for (int blk = 0; blk < 4; blk++) {
        short8 pa, bv;
#pragma unroll
        for (int jj = 0; jj < 4; jj++) {
            const h2 t = sh[blk * 4 + jj];
            const float e0 = __expf((float)t.x - m_l);
            const float e1 = __expf((float)t.y - m_l);
            lsum += e0 + e1;
            const bf162 pr = __float22bfloat162_rn(make_float2(e0, e1));
            pa[2 * jj]     = __builtin_bit_cast(short, pr.x);
            pa[2 * jj + 1] = __builtin_bit_cast(short, pr.y);
        }
#pragma unroll
        for (int j = 0; j < 8; j++) bv[j] = vbuf[(blk * 32 + quad * 8 + j) * 16 + fr];
        oacc = __builtin_amdgcn_mfma_f32_16x16x32_bf16(pa, bv, oacc, 0, 0, 0);
    }
    lsum += __shfl_xor(lsum, 16, 64);
    lsum += __shfl_xor(lsum, 32, 64);

    // ---- write normalized per-cs partial + true l ----
    const int idxbase = cs * 32768 + ((b * H_ + h) << 9) + rt * 64 + wid * 16;
    if (quad == 0) plf[idxbase + fr] = lsum * __expf(m_l);
#pragma unroll
    for (int i = 0; i < 4; i++) {
        const float li = __shfl(lsum, quad * 4 + i, 64);
        po[(size_t)(idxbase + quad * 4 + i) * 16 + fr] = __float2bfloat16(oacc[i] / li);
    }
}

// ================= K3: 4-way weighted merge of normalized partials -> sa; zero stats =================
__global__ __launch_bounds__(256) void attn_merge_kernel(
    const bf16* __restrict__ po, const float* __restrict__ plf, bf16* __restrict__ sa,
    float* __restrict__ stats1, float* __restrict__ stats2)
{
    const int idx = blockIdx.x * 256 + threadIdx.x;  // 32768
    if (idx < 2048) stats1[idx] = 0.f;
    else if (idx < 4096) stats2[idx - 2048] = 0.f;
    const float l0 = plf[idx], l1 = plf[32768 + idx];
    const float l2 = plf[65536 + idx], l3 = plf[98304 + idx];
    const float inv = 1.f / (l0 + l1 + l2 + l3);
    float oo[16] = {};
#pragma unroll
    for (int c = 0; c < 4; c++) {
        const float wgt = ((c == 0) ? l0 : (c == 1) ? l1 : (c == 2) ? l2 : l3) * inv;
        const bf162* pp = (const bf162*)(po + (size_t)(c * 32768 + idx) * 16);
#pragma unroll
        for (int j = 0; j < 8; j++) {
            const float2 f = __bfloat1622float2(pp[j]);
            oo[2 * j]     = fmaf(wgt, f.x, oo[2 * j]);
            oo[2 * j + 1] = fmaf(wgt, f.y, oo[2 * j + 1]);
        }
    }
    const int b = idx >> 13, h = (idx >> 9) & 15, r = idx & 511;
    bf162* dst = (bf162*)(sa + (size_t)(b * R_ + r) * 256 + h * 16);
#pragma unroll
    for (int j = 0; j < 8; j++)
        dst[j] = __float22bfloat162_rn(make_float2(oo[2 * j], oo[2 * j + 1]));
}

// ================= K7: final instance-norm from raw stats -> fp32 out =================
__global__ __launch_bounds__(256) void apply_in2_kernel(
    const bf16* __restrict__ xin, const float* __restrict__ stats,
    const float* __restrict__ g, const float* __restrict__ be, float* __restrict__ outp)
{
    const int base = (blockIdx.x * 256 + threadIdx.x) * 4;  // < 524288
    const int b = base >> 17;
    const bf162* xp = (const bf162*)(xin + base);
    const float2 x0 = __bfloat1622float2(xp[0]), x1 = __bfloat1622float2(xp[1]);
    const float xv[4] = {x0.x, x0.y, x1.x, x1.y};
    float4 rr;
    float* rp = (float*)&rr;
#pragma unroll
    for (int j = 0; j < 4; j++) {
        const int e = (base & 255) + j;
        const float s = stats[b * 256 + e], sq = stats[1024 + b * 256 + e];
        const float mn = s * (1.f / 512.f);
        float var = sq * (1.f / 512.f) - mn * mn; var = fmaxf(var, 0.f);
        rp[j] = (xv[j] - mn) * rsqrtf(var + 1e-5f) * g[e] + be[e];
    }
    *(float4*)(outp + base) = rr;
}

extern "C" void kernel_launch(void* const* d_in, const int* in_sizes, int n_in,
                              void* d_out, int out_size, void* d_ws, size_t ws_size,
                              hipStream_t stream)
{
    (void)in_sizes; (void)n_in; (void)out_size; (void)ws_size;
    const float* row_emb = (const float*)d_in[0];
    const float* col_emb = (const float*)d_in[1];
    const float* cost    = (const float*)d_in[2];
    const float* Wq  = (const float*)d_in[3];
    const float* Wk  = (const float*)d_in[4];
    const float* Wv  = (const float*)d_in[5];
    const float* m1w = (const float*)d_in[6];
    const float* m1b = (const float*)d_in[7];
    const float* m2w = (const float*)d_in[8];
    const float* m2b = (const float*)d_in[9];
    const float* Wc  = (const float*)d_in[10];
    const float* bc  = (const float*)d_in[11];
    const float* W1  = (const float*)d_in[12];
    const float* b1  = (const float*)d_in[13];
    const float* W2  = (const float*)d_in[14];
    const float* b2  = (const float*)d_in[15];
    const float* g1  = (const float*)d_in[16];
    const float* be1 = (const float*)d_in[17];
    const float* g2  = (const float*)d_in[18];
    const float* be2 = (const float*)d_in[19];
    float* out = (float*)d_out;

    // ---- workspace layout (~8.3 MB used) ----
    char* w = (char*)d_ws;
    f16*  sq  = (f16*)(w + 0);             // [K1..K2]
    f16*  sk  = (f16*)(w + 1048576);       // [K1..K2]
    bf16* sv  = (bf16*)(w + 2097152);      // [K1..K2]
    bf16* sa  = (bf16*)(w + 0);            // [K3..K4] (sq dead)
    bf16* sy  = (bf16*)(w + 1048576);      // [K4..K6] (sk dead)
    bf16* st  = (bf16*)(w + 2097152);      // [K6..K7] (sv dead)
    bf16* po  = (bf16*)(w + 3145728);      // 4 MB [K2..K3]
    bf16* shm = (bf16*)(w + 3145728);      // 2 MB [K5..K6] (po dead)
    float* plf = (float*)(w + 7340032);    // 512 KB [K2..K3]
    float* stats1 = (float*)(w + 8257536); // 8 KB
    float* stats2 = stats1 + 2048;         // 8 KB

    const dim3 blk(256);

    // K1: QKV (direct fp32 weights, transpose-on-stage; q pre-scaled 0.25)
    qkv_kernel<<<dim3(4, 64, 3), blk, 0, stream>>>(row_emb, col_emb, Wq, Wk, Wv, sq, sk, sv);

    // K2: attention partials (2048 WGs, 8.2 KB LDS, MFMA PV)
    attn_kernel<<<dim3(32, 16, 4), blk, 0, stream>>>(
        sq, sk, sv, cost, m1w, m1b, m2w, m2b, po, plf);

    // K3: merge -> sa; zero stats1/stats2 for the downstream atomics
    attn_merge_kernel<<<dim3(128), blk, 0, stream>>>(po, plf, sa, stats1, stats2);

    // K4: y = sa @ Wc + bc + row_emb -> sy (+stats1)  [512 WGs]
    mfma_gemm_kernel<0, bf16, 32, 32, true, 1, false, true><<<dim3(8, 64), blk, 0, stream>>>(
        sa, Wc, 1.f, bc, row_emb, nullptr, nullptr, nullptr, stats1, sy, 2048, 256, 256);

    // K5: hm = relu(norm1(sy) @ W1 + b1) -> shm  [512 WGs]
    mfma_gemm_kernel<2, bf16, 32, 64, true, 0, true, false><<<dim3(8, 64), blk, 0, stream>>>(
        sy, W1, 1.f, b1, nullptr, stats1, g1, be1, nullptr, shm, 2048, 512, 256);

    // K6: t = hm @ W2 + b2 + norm1(sy) -> st (+stats2)  [512 WGs]
    mfma_gemm_kernel<0, bf16, 32, 32, true, 3, false, true><<<dim3(8, 64), blk, 0, stream>>>(
        shm, W2, 1.f, b2, sy, stats1, g1, be1, stats2, st, 2048, 256, 512);

    // K7: out = norm2(st)
    apply_in2_kernel<<<dim3(512), blk, 0, stream>>>(st, stats2, g2, be2, out);
}

// Round 15
// 160.893 us; speedup vs baseline: 1.0889x; 1.0889x over previous
//
#include <hip/hip_runtime.h>
#include <hip/hip_bf16.h>

typedef __hip_bfloat16 bf16;
typedef __hip_bfloat162 bf162;
typedef _Float16 f16;
typedef __attribute__((ext_vector_type(2))) _Float16 h2;
typedef __attribute__((ext_vector_type(8))) short short8;
typedef __attribute__((ext_vector_type(4))) float f32x4;

#define B_ 4
#define R_ 512
#define C_ 512
#define E_ 256
#define H_ 16
#define D_ 16

__device__ __forceinline__ float b2f(bf16 x) { return __bfloat162float(x); }
__device__ __forceinline__ void stout(bf16* p, float v) { *p = __float2bfloat16(v); }
__device__ __forceinline__ void stout(f16* p, float v) { *p = (f16)v; }

// ================= K1: weight transpose/cvt fp32[K][N] -> bf16[N][K]; spares zero stats =================
// Wq pre-scaled by 1/sqrt(D)=0.25.
__global__ __launch_bounds__(256) void transpose_cvt_kernel(
    const float* __restrict__ Wq, const float* __restrict__ Wk, const float* __restrict__ Wv,
    const float* __restrict__ Wc, const float* __restrict__ W1, const float* __restrict__ W2,
    bf16* __restrict__ WqT, bf16* __restrict__ WkT, bf16* __restrict__ WvT,
    bf16* __restrict__ WcT, bf16* __restrict__ W1T, bf16* __restrict__ W2T,
    float* __restrict__ statsZ)
{
    __shared__ bf16 tile[32][33];
    const int wsel = blockIdx.y;
    const int tx = blockIdx.x;
    if (wsel == 0 && tx >= 64) {  // spare blocks zero stats1+stats2 (4096 floats)
        const int idx = (tx - 64) * 256 + threadIdx.x;
        if (idx < 4096) statsZ[idx] = 0.f;
        return;
    }
    const float* src; bf16* dst; int K, N; float scl = 1.0f;
    switch (wsel) {
        case 0: src = Wq; dst = WqT; K = 256; N = 256; scl = 0.25f; break;
        case 1: src = Wk; dst = WkT; K = 256; N = 256; break;
        case 2: src = Wv; dst = WvT; K = 256; N = 256; break;
        case 3: src = Wc; dst = WcT; K = 256; N = 256; break;
        case 4: src = W1; dst = W1T; K = 256; N = 512; break;
        default: src = W2; dst = W2T; K = 512; N = 256; break;
    }
    const int ntiles = (K >> 5) * (N >> 5);
    if (tx >= ntiles) return;
    const int ncnt = N >> 5;
    const int tk = tx / ncnt, tn = tx % ncnt;
    const int c = threadIdx.x & 31, r = threadIdx.x >> 5;
#pragma unroll
    for (int i = 0; i < 4; i++)
        tile[r + i * 8][c] = __float2bfloat16(scl * src[(size_t)(tk * 32 + r + i * 8) * N + tn * 32 + c]);
    __syncthreads();
#pragma unroll
    for (int i = 0; i < 4; i++)
        dst[(size_t)(tn * 32 + r + i * 8) * K + tk * 32 + c] = tile[c][r + i * 8];
}

// ================= MFMA GEMM body (pre-transposed bf16 B [N][K]) =================
// AMODE: 0 = bf16 A, 1 = fp32 A (cvt), 2 = instance-norm bf16 A (normS,g,b)
// RES: 0 none, 1 fp32 ptr, 3 instance-norm(bf16 Res); STATS: sum/sumsq atomics
template <int AMODE, typename OT, int BM, int BN, bool BIAS, int RES, bool RELU, bool STATS>
__device__ __forceinline__ void mfma_gemm_body(
    const void* __restrict__ Ap, const bf16* __restrict__ BT,
    const float* __restrict__ bias, const void* __restrict__ Res,
    const float* __restrict__ normS, const float* __restrict__ normG, const float* __restrict__ normB,
    float* __restrict__ statsOut, OT* __restrict__ Cout,
    int M, int N, int K, int bx, int by)
{
    constexpr int MT = BM / 32, NT = BN / 32;
    constexpr int AEL = BM * 64 / 256, BEL = BN * 64 / 256;
    __shared__ __align__(16) bf16 As[BM * 80];
    __shared__ __align__(16) bf16 Bs[BN * 80];
    const int tid = threadIdx.x;
    const int wid = tid >> 6, lane = tid & 63;
    const int wm = wid >> 1, wn = wid & 1;
    const int fr = lane & 15, quad = lane >> 4;
    const int m0 = by * BM, n0 = bx * BN;
    const int arow = (AEL == 16) ? (tid >> 2) : (tid >> 3);
    const int akg  = (AEL == 16) ? ((tid & 3) << 4) : ((tid & 7) << 3);
    const int brow = (BEL == 16) ? (tid >> 2) : (tid >> 3);
    const int bkg  = (BEL == 16) ? ((tid & 3) << 4) : ((tid & 7) << 3);

    f32x4 acc[MT][NT];
#pragma unroll
    for (int mt = 0; mt < MT; mt++)
#pragma unroll
        for (int nt = 0; nt < NT; nt++) acc[mt][nt] = (f32x4){0.f, 0.f, 0.f, 0.f};

    for (int k0 = 0; k0 < K; k0 += 64) {
        // ---- stage A ----
        if constexpr (AMODE == 0) {
            const short8* gp = (const short8*)((const bf16*)Ap + (size_t)(m0 + arow) * K + k0 + akg);
#pragma unroll
            for (int t8 = 0; t8 < AEL / 8; t8++) *(short8*)(&As[arow * 80 + akg + 8 * t8]) = gp[t8];
        } else if constexpr (AMODE == 1) {
            const float4* gp = (const float4*)((const float*)Ap + (size_t)(m0 + arow) * K + k0 + akg);
#pragma unroll
            for (int j = 0; j < AEL / 4; j++) {
                const float4 f = gp[j];
                *(bf162*)(&As[arow * 80 + akg + j * 4])     = __float22bfloat162_rn(make_float2(f.x, f.y));
                *(bf162*)(&As[arow * 80 + akg + j * 4 + 2]) = __float22bfloat162_rn(make_float2(f.z, f.w));
            }
        } else {  // AMODE == 2: instance-norm A
            const int bb = (m0 + arow) >> 9;
            const bf16* ap = (const bf16*)Ap + (size_t)(m0 + arow) * K + k0 + akg;
            bf16 tmp[AEL];
#pragma unroll
            for (int t8 = 0; t8 < AEL / 8; t8++) *(short8*)(tmp + 8 * t8) = ((const short8*)ap)[t8];
#pragma unroll
            for (int j = 0; j < AEL; j++) {
                const int e = k0 + akg + j;
                const float s = normS[bb * 256 + e], sq = normS[1024 + bb * 256 + e];
                const float mn = s * (1.f / 512.f);
                float var = sq * (1.f / 512.f) - mn * mn; var = fmaxf(var, 0.f);
                As[arow * 80 + akg + j] = __float2bfloat16(
                    (b2f(tmp[j]) - mn) * rsqrtf(var + 1e-5f) * normG[e] + normB[e]);
            }
        }
        // ---- stage B: coalesced short8 from pre-transposed BT [N][K] ----
        {
            const short8* gp = (const short8*)(BT + (size_t)(n0 + brow) * K + k0 + bkg);
#pragma unroll
            for (int t8 = 0; t8 < BEL / 8; t8++) *(short8*)(&Bs[brow * 80 + bkg + 8 * t8]) = gp[t8];
        }
        __syncthreads();

        short8 af[MT][2], bfr[NT][2];
#pragma unroll
        for (int mt = 0; mt < MT; mt++) {
            const int ar = wm * (BM / 2) + mt * 16 + fr;
#pragma unroll
            for (int kh = 0; kh < 2; kh++)
                af[mt][kh] = *(const short8*)(&As[ar * 80 + quad * 8 + kh * 32]);
        }
#pragma unroll
        for (int nt = 0; nt < NT; nt++) {
            const int br = wn * (BN / 2) + nt * 16 + fr;
#pragma unroll
            for (int kh = 0; kh < 2; kh++)
                bfr[nt][kh] = *(const short8*)(&Bs[br * 80 + quad * 8 + kh * 32]);
        }
#pragma unroll
        for (int kh = 0; kh < 2; kh++)
#pragma unroll
            for (int mt = 0; mt < MT; mt++)
#pragma unroll
                for (int nt = 0; nt < NT; nt++)
                    acc[mt][nt] = __builtin_amdgcn_mfma_f32_16x16x32_bf16(
                        af[mt][kh], bfr[nt][kh], acc[mt][nt], 0, 0, 0);
        __syncthreads();
    }

    // ---- epilogue (C/D: col=lane&15, row=quad*4+reg) ----
    float vsum[NT], vss[NT];
#pragma unroll
    for (int nt = 0; nt < NT; nt++) { vsum[nt] = 0.f; vss[nt] = 0.f; }
#pragma unroll
    for (int mt = 0; mt < MT; mt++) {
#pragma unroll
        for (int nt = 0; nt < NT; nt++) {
#pragma unroll
            for (int i = 0; i < 4; i++) {
                const int row = m0 + wm * (BM / 2) + mt * 16 + quad * 4 + i;
                const int col = n0 + wn * (BN / 2) + nt * 16 + fr;
                float v = acc[mt][nt][i];
                if (BIAS) v += bias[col];
                if constexpr (RES == 1) v += ((const float*)Res)[(size_t)row * N + col];
                if constexpr (RES == 3) {
                    const int bb = row >> 9;
                    const float yv = b2f(((const bf16*)Res)[(size_t)row * N + col]);
                    const float s = normS[bb * 256 + col], sq = normS[1024 + bb * 256 + col];
                    const float mn = s * (1.f / 512.f);
                    float var = sq * (1.f / 512.f) - mn * mn; var = fmaxf(var, 0.f);
                    v += (yv - mn) * rsqrtf(var + 1e-5f) * normG[col] + normB[col];
                }
                if (RELU) v = fmaxf(v, 0.f);
                stout(&Cout[(size_t)row * N + col], v);
                if (STATS) { vsum[nt] += v; vss[nt] += v * v; }
            }
        }
    }
    if constexpr (STATS) {
        float* sred = (float*)As;  // alias dead A-tile
#pragma unroll
        for (int nt = 0; nt < NT; nt++) {
            float a = vsum[nt]; a += __shfl_xor(a, 16, 64); a += __shfl_xor(a, 32, 64);
            float c = vss[nt];  c += __shfl_xor(c, 16, 64); c += __shfl_xor(c, 32, 64);
            if (quad == 0) {
                const int cl = wn * (BN / 2) + nt * 16 + fr;
                sred[wm * (2 * BN) + cl * 2 + 0] = a;
                sred[wm * (2 * BN) + cl * 2 + 1] = c;
            }
        }
        __syncthreads();
        if (tid < 2 * BN) {
            const int cl = tid >> 1, w = tid & 1;
            const float tot = sred[cl * 2 + w] + sred[2 * BN + cl * 2 + w];
            atomicAdd(&statsOut[w * 1024 + (m0 >> 9) * 256 + n0 + cl], tot);
        }
    }
}

template <int AMODE, typename OT, int BM, int BN, bool BIAS, int RES, bool RELU, bool STATS>
__global__ __launch_bounds__(256) void mfma_gemm_kernel(
    const void* __restrict__ Ap, const bf16* __restrict__ BT,
    const float* __restrict__ bias, const void* __restrict__ Res,
    const float* __restrict__ normS, const float* __restrict__ normG, const float* __restrict__ normB,
    float* __restrict__ statsOut, OT* __restrict__ Cout, int M, int N, int K)
{
    mfma_gemm_body<AMODE, OT, BM, BN, BIAS, RES, RELU, STATS>(
        Ap, BT, bias, Res, normS, normG, normB, statsOut, Cout,
        M, N, K, blockIdx.x, blockIdx.y);
}

// ================= K2: fused QKV; q,k -> f16, v -> bf16 (768 WGs) =================
__global__ __launch_bounds__(256) void qkv_kernel(
    const float* __restrict__ rowE, const float* __restrict__ colE,
    const bf16* __restrict__ WqT, const bf16* __restrict__ WkT, const bf16* __restrict__ WvT,
    f16* __restrict__ qo, f16* __restrict__ ko, bf16* __restrict__ vo)
{
    const int z = blockIdx.z;
    if (z == 2) {
        mfma_gemm_body<1, bf16, 32, 64, false, 0, false, false>(
            colE, WvT, nullptr, nullptr, nullptr, nullptr, nullptr, nullptr, vo,
            2048, 256, 256, blockIdx.x, blockIdx.y);
    } else {
        mfma_gemm_body<1, f16, 32, 64, false, 0, false, false>(
            (z == 0) ? rowE : colE, (z == 0) ? WqT : WkT,
            nullptr, nullptr, nullptr, nullptr, nullptr, nullptr, (z == 0) ? qo : ko,
            2048, 256, 256, blockIdx.x, blockIdx.y);
    }
}

// ================= K3: attention with MFMA PV; grid (rt8 x cs4, h16, b4) = 2048 WGs =================
// Wave w owns rows [rt*64+w*16, +16) x 128 cols. Lane computes scores at A-frag
// positions (m=lane&15, k=quad*8+j): its 8 softmax weights ARE the MFMA A-fragment.
// V is the B-fragment (k=quad*8+j, n=lane&15); O accumulates in C-regs
// (row=quad*4+i, col=lane&15). Two-pass per-row max -> p in (0,1] fits bf16.
// No intra-WG merge (waves own disjoint rows). 8.2 KB LDS.
__global__ __launch_bounds__(256) void attn_kernel(
    const f16* __restrict__ q, const f16* __restrict__ k, const bf16* __restrict__ v,
    const float* __restrict__ cost, const float* __restrict__ m1w, const float* __restrict__ m1b,
    const float* __restrict__ m2w, const float* __restrict__ m2b,
    bf16* __restrict__ po, float* __restrict__ plf)
{
    __shared__ __align__(16) f16 kbuf[128 * 16];    // 4 KB
    __shared__ __align__(16) short vbuf[128 * 16];  // 4 KB (bf16 bits)

    const int rt = blockIdx.x >> 2, cs = blockIdx.x & 3;
    const int h = blockIdx.y, b = blockIdx.z;
    const int tid = threadIdx.x, wid = tid >> 6, lane = tid & 63;
    const int quad = lane >> 4, fr = lane & 15;

    // ---- stage k (f16) and v (bf16): straight copies ----
    {
        const size_t base = ((size_t)b * C_) * 256 + h * 16 + (size_t)cs * 128 * 256;
        const int lc = tid >> 1, dp = (tid & 1) * 8;
        const size_t g = base + (size_t)lc * 256 + dp;
        *(short8*)(&kbuf[lc * 16 + dp]) = *(const short8*)(k + g);
        *(short8*)(&vbuf[lc * 16 + dp]) = *(const short8*)(v + g);
    }

    // per-head MLP weights (packed f16 pairs over m)
    h2 w1a2[8], w1b2[8], b1h[8], w2p[8];
#pragma unroll
    for (int i = 0; i < 8; i++) {
        h2 t;
        t.x = (f16)m1w[h * 32 + 2 * i];      t.y = (f16)m1w[h * 32 + 2 * i + 1];      w1a2[i] = t;
        t.x = (f16)m1w[h * 32 + 16 + 2 * i]; t.y = (f16)m1w[h * 32 + 17 + 2 * i];     w1b2[i] = t;
        t.x = (f16)m1b[h * 16 + 2 * i];      t.y = (f16)m1b[h * 16 + 2 * i + 1];      b1h[i] = t;
        t.x = (f16)m2w[h * 16 + 2 * i];      t.y = (f16)m2w[h * 16 + 2 * i + 1];      w2p[i] = t;
    }
    const float b2v = m2b[h];
    const h2 zero2 = (h2)(f16)0;

    // this lane's q row (Wq carries the 0.25 scale)
    const int row_m = rt * 64 + wid * 16 + fr;
    short8 qraw[2];
    {
        const short8* qp = (const short8*)(q + (size_t)(b * R_ + row_m) * 256 + h * 16);
        qraw[0] = qp[0]; qraw[1] = qp[1];
    }
    const h2* qh = (const h2*)qraw;

    __syncthreads();

    // ---- pass 1: 32 scores at A-frag positions, buffered f16 ----
    const float* crow = cost + (size_t)(b * R_ + row_m) * C_ + cs * 128;
    h2 sh[16];
#pragma unroll
    for (int blk = 0; blk < 4; blk++) {
        const float4 c0 = *(const float4*)(crow + blk * 32 + quad * 8);
        const float4 c1 = *(const float4*)(crow + blk * 32 + quad * 8 + 4);
        const float carr[8] = {c0.x, c0.y, c0.z, c0.w, c1.x, c1.y, c1.z, c1.w};
#pragma unroll
        for (int j = 0; j < 8; j++) {
            const int col = blk * 32 + quad * 8 + j;
            const h2* kr = (const h2*)(&kbuf[col * 16]);
            h2 dacc = qh[0] * kr[0];
#pragma unroll
            for (int i = 1; i < 8; i++) dacc = qh[i] * kr[i] + dacc;
            const float dot = (float)dacc.x + (float)dacc.y;
            const float cst = carr[j];
            const f16 doth = (f16)dot, csth = (f16)cst;
            h2 dot2; dot2.x = doth; dot2.y = doth;
            h2 cst2; cst2.x = csth; cst2.y = csth;
            h2 acc2 = (h2)(f16)0;
#pragma unroll
            for (int i = 0; i < 8; i++) {
                h2 t = dot2 * w1a2[i] + b1h[i];
                t = cst2 * w1b2[i] + t;
                t = __builtin_elementwise_max(t, zero2);
                acc2 = t * w2p[i] + acc2;
            }
            const float s = b2v + (float)acc2.x + (float)acc2.y;
            const f16 sf = (f16)s;
            if (j & 1) sh[blk * 4 + (j >> 1)].y = sf;
            else       sh[blk * 4 + (j >> 1)].x = sf;
        }
    }

    // ---- row max (row = fr, shared across quads) ----
    h2 mx2 = sh[0];
#pragma unroll
    for (int i = 1; i < 16; i++) mx2 = __builtin_elementwise_max(mx2, sh[i]);
    float m_l = fmaxf((float)mx2.x, (float)mx2.y);
    m_l = fmaxf(m_l, __shfl_xor(m_l, 16, 64));
    m_l = fmaxf(m_l, __shfl_xor(m_l, 32, 64));

    // ---- pass 2: exp -> bf16 A-frag, V B-frag, MFMA PV ----
    f32x4 oacc = (f32x4){0.f, 0.f, 0.f, 0.f};
    float lsum = 0.f;
#pragma unroll
    for (int blk = 0; blk < 4; blk++) {
        short8 pa, bv;
#pragma unroll
        for (int jj = 0; jj < 4; jj++) {
            const h2 t = sh[blk * 4 + jj];
            const float e0 = __expf((float)t.x - m_l);
            const float e1 = __expf((float)t.y - m_l);
            lsum += e0 + e1;
            const bf162 pr = __float22bfloat162_rn(make_float2(e0, e1));
            pa[2 * jj]     = __builtin_bit_cast(short, pr.x);
            pa[2 * jj + 1] = __builtin_bit_cast(short, pr.y);
        }
#pragma unroll
        for (int j = 0; j < 8; j++) bv[j] = vbuf[(blk * 32 + quad * 8 + j) * 16 + fr];
        oacc = __builtin_amdgcn_mfma_f32_16x16x32_bf16(pa, bv, oacc, 0, 0, 0);
    }
    lsum += __shfl_xor(lsum, 16, 64);
    lsum += __shfl_xor(lsum, 32, 64);

    // ---- write normalized per-cs partial + true l ----
    const int idxbase = cs * 32768 + ((b * H_ + h) << 9) + rt * 64 + wid * 16;
    if (quad == 0) plf[idxbase + fr] = lsum * __expf(m_l);
#pragma unroll
    for (int i = 0; i < 4; i++) {
        const float li = __shfl(lsum, quad * 4 + i, 64);
        po[(size_t)(idxbase + quad * 4 + i) * 16 + fr] = __float2bfloat16(oacc[i] / li);
    }
}

// ================= K3b: 4-way weighted merge of normalized partials -> sa =================
__global__ __launch_bounds__(256) void attn_merge_kernel(
    const bf16* __restrict__ po, const float* __restrict__ plf, bf16* __restrict__ sa)
{
    const int idx = blockIdx.x * 256 + threadIdx.x;  // 32768
    const float l0 = plf[idx], l1 = plf[32768 + idx];
    const float l2 = plf[65536 + idx], l3 = plf[98304 + idx];
    const float inv = 1.f / (l0 + l1 + l2 + l3);
    float oo[16] = {};
#pragma unroll
    for (int c = 0; c < 4; c++) {
        const float wgt = ((c == 0) ? l0 : (c == 1) ? l1 : (c == 2) ? l2 : l3) * inv;
        const bf162* pp = (const bf162*)(po + (size_t)(c * 32768 + idx) * 16);
#pragma unroll
        for (int j = 0; j < 8; j++) {
            const float2 f = __bfloat1622float2(pp[j]);
            oo[2 * j]     = fmaf(wgt, f.x, oo[2 * j]);
            oo[2 * j + 1] = fmaf(wgt, f.y, oo[2 * j + 1]);
        }
    }
    const int b = idx >> 13, h = (idx >> 9) & 15, r = idx & 511;
    bf162* dst = (bf162*)(sa + (size_t)(b * R_ + r) * 256 + h * 16);
#pragma unroll
    for (int j = 0; j < 8; j++)
        dst[j] = __float22bfloat162_rn(make_float2(oo[2 * j], oo[2 * j + 1]));
}

// ================= K7: final instance-norm from raw stats -> fp32 out =================
__global__ __launch_bounds__(256) void apply_in2_kernel(
    const bf16* __restrict__ xin, const float* __restrict__ stats,
    const float* __restrict__ g, const float* __restrict__ be, float* __restrict__ outp)
{
    const int base = (blockIdx.x * 256 + threadIdx.x) * 4;  // < 524288
    const int b = base >> 17;
    const bf162* xp = (const bf162*)(xin + base);
    const float2 x0 = __bfloat1622float2(xp[0]), x1 = __bfloat1622float2(xp[1]);
    const float xv[4] = {x0.x, x0.y, x1.x, x1.y};
    float4 rr;
    float* rp = (float*)&rr;
#pragma unroll
    for (int j = 0; j < 4; j++) {
        const int e = (base & 255) + j;
        const float s = stats[b * 256 + e], sq = stats[1024 + b * 256 + e];
        const float mn = s * (1.f / 512.f);
        float var = sq * (1.f / 512.f) - mn * mn; var = fmaxf(var, 0.f);
        rp[j] = (xv[j] - mn) * rsqrtf(var + 1e-5f) * g[e] + be[e];
    }
    *(float4*)(outp + base) = rr;
}

extern "C" void kernel_launch(void* const* d_in, const int* in_sizes, int n_in,
                              void* d_out, int out_size, void* d_ws, size_t ws_size,
                              hipStream_t stream)
{
    (void)in_sizes; (void)n_in; (void)out_size; (void)ws_size;
    const float* row_emb = (const float*)d_in[0];
    const float* col_emb = (const float*)d_in[1];
    const float* cost    = (const float*)d_in[2];
    const float* Wq  = (const float*)d_in[3];
    const float* Wk  = (const float*)d_in[4];
    const float* Wv  = (const float*)d_in[5];
    const float* m1w = (const float*)d_in[6];
    const float* m1b = (const float*)d_in[7];
    const float* m2w = (const float*)d_in[8];
    const float* m2b = (const float*)d_in[9];
    const float* Wc  = (const float*)d_in[10];
    const float* bc  = (const float*)d_in[11];
    const float* W1  = (const float*)d_in[12];
    const float* b1  = (const float*)d_in[13];
    const float* W2  = (const float*)d_in[14];
    const float* b2  = (const float*)d_in[15];
    const float* g1  = (const float*)d_in[16];
    const float* be1 = (const float*)d_in[17];
    const float* g2  = (const float*)d_in[18];
    const float* be2 = (const float*)d_in[19];
    float* out = (float*)d_out;

    // ---- workspace layout (ws ~256 MB per fill trace; ~10 MB used) ----
    char* w = (char*)d_ws;
    const size_t MB = 1u << 20;
    f16*  sq  = (f16*)(w + 0 * MB);        // [K2..K3]
    f16*  sk  = (f16*)(w + 1 * MB);        // [K2..K3]
    bf16* sv  = (bf16*)(w + 2 * MB);       // [K2..K3]
    bf16* sa  = (bf16*)(w + 0 * MB);       // [K3b..K4] (sq dead)
    bf16* sy  = (bf16*)(w + 1 * MB);       // [K4..K6] (sk dead)
    bf16* st  = (bf16*)(w + 2 * MB);       // [K6..K7] (sv dead)
    bf16* po  = (bf16*)(w + 3 * MB);       // 4 MB [K3..K3b]
    bf16* shm = (bf16*)(w + 3 * MB);       // 2 MB [K5..K6] (po dead)
    float* plf = (float*)(w + 7 * MB);     // 512 KB [K3..K3b]
    bf16* WqT = (bf16*)(w + 8 * MB);       // 128 KB each for Wq/Wk/Wv/Wc
    bf16* WkT = WqT + 65536;
    bf16* WvT = WkT + 65536;
    bf16* WcT = WvT + 65536;
    bf16* W1T = WcT + 65536;               // 256 KB
    bf16* W2T = W1T + 131072;              // 256 KB
    float* stats1 = (float*)(w + 9 * MB);  // 8 KB
    float* stats2 = stats1 + 2048;         // 8 KB

    const dim3 blk(256);

    // K1: weight transpose/cvt (Wq pre-scaled 0.25) + zero stats
    transpose_cvt_kernel<<<dim3(128, 6), blk, 0, stream>>>(
        Wq, Wk, Wv, Wc, W1, W2, WqT, WkT, WvT, WcT, W1T, W2T, stats1);

    // K2: QKV; q,k -> f16, v -> bf16
    qkv_kernel<<<dim3(4, 64, 3), blk, 0, stream>>>(row_emb, col_emb, WqT, WkT, WvT, sq, sk, sv);

    // K3: attention partials (2048 WGs, 8.2 KB LDS, MFMA PV)
    attn_kernel<<<dim3(32, 16, 4), blk, 0, stream>>>(
        sq, sk, sv, cost, m1w, m1b, m2w, m2b, po, plf);

    // K3b: merge -> sa
    attn_merge_kernel<<<dim3(128), blk, 0, stream>>>(po, plf, sa);

    // K4: y = sa @ Wc + bc + row_emb -> sy (+stats1)  [512 WGs]
    mfma_gemm_kernel<0, bf16, 32, 32, true, 1, false, true><<<dim3(8, 64), blk, 0, stream>>>(
        sa, WcT, bc, row_emb, nullptr, nullptr, nullptr, stats1, sy, 2048, 256, 256);

    // K5: hm = relu(norm1(sy) @ W1 + b1) -> shm  [512 WGs]
    mfma_gemm_kernel<2, bf16, 32, 64, true, 0, true, false><<<dim3(8, 64), blk, 0, stream>>>(
        sy, W1T, b1, nullptr, stats1, g1, be1, nullptr, shm, 2048, 512, 256);

    // K6: t = hm @ W2 + b2 + norm1(sy) -> st (+stats2)  [512 WGs]
    mfma_gemm_kernel<0, bf16, 32, 32, true, 3, false, true><<<dim3(8, 64), blk, 0, stream>>>(
        shm, W2T, b2, sy, stats1, g1, be1, stats2, st, 2048, 256, 512);

    // K7: out = norm2(st)
    apply_in2_kernel<<<dim3(512), blk, 0, stream>>>(st, stats2, g2, be2, out);
}